// Round 3
// baseline (226.053 us; speedup 1.0000x reference)
//
#include <hip/hip_runtime.h>
#include <hip/hip_bf16.h>
#include <stdint.h>

#define D 128
#define SEQ 2048
#define NH 16
#define KVB 64
#define NTILE 32
#define BLOCK_Q 128   // q rows per block
#define QT 64         // q rows per warp (2 subtiles of 32)

typedef float f32x4  __attribute__((ext_vector_type(4)));
typedef float f32x16 __attribute__((ext_vector_type(16)));
typedef short bf16x8 __attribute__((ext_vector_type(8)));

__device__ __forceinline__ unsigned cvtpk(float lo, float hi){
    unsigned r;
    asm("v_cvt_pk_bf16_f32 %0, %1, %2" : "=v"(r) : "v"(lo), "v"(hi));
    return r;
}

// ---------------- prep: f32 -> bf16 pre-swizzled LDS tile images in ws ----------
// wsK1 [0,2MB):   chunk addr = grow*256 + c16*16, content = K1[grow][(c16^(grow&7))*8 ..+8]
// wsK2 [2MB,4MB): same for k2
// wsV  [4MB,6MB): chunk c = d*8+c16 of tile: content = V[t*64 + (c16^(d&7))*8 + j][d], j=0..7
#define VSTRIDE 130
__global__ __launch_bounds__(256) void prep(const float* __restrict__ k1,
                                            const float* __restrict__ k2,
                                            const float* __restrict__ v,
                                            char* __restrict__ ws)
{
    __shared__ unsigned short vlds[64 * VSTRIDE];
    const int b = blockIdx.x;
    if (b < 1024){
        int cid = b * 256 + threadIdx.x;          // 0..262143
        const float* src = (cid & 131072) ? k2 : k1;
        int r    = cid & 131071;
        int grow = r >> 4;
        int c16  = r & 15;
        const float* p = src + (size_t)grow * D + ((c16 ^ (grow & 7)) << 3);
        f32x4 a = *(const f32x4*)p;
        f32x4 c = *(const f32x4*)(p + 4);
        uint4 w;
        w.x = cvtpk(a[0], a[1]); w.y = cvtpk(a[2], a[3]);
        w.z = cvtpk(c[0], c[1]); w.w = cvtpk(c[2], c[3]);
        *(uint4*)(ws + (size_t)cid * 16) = w;
    } else {
        const int vt  = b - 1024;                 // 0..127 : kvh*32 + t
        const int tid = threadIdx.x;
        const size_t gkb = (size_t)vt * 64;       // global V row base
        // load phase: coalesced rows -> LDS bf16 [64][VSTRIDE]
        const int key = tid >> 2, cg = tid & 3;
        const float* vp = v + (gkb + key) * D + cg * 32;
        #pragma unroll
        for (int i = 0; i < 8; ++i){
            f32x4 x = *(const f32x4*)(vp + i * 4);
            unsigned lo = cvtpk(x[0], x[1]);
            unsigned hi = cvtpk(x[2], x[3]);
            unsigned* dst = (unsigned*)&vlds[key * VSTRIDE + cg * 32 + i * 4];
            dst[0] = lo; dst[1] = hi;
        }
        __syncthreads();
        // store phase: gather columns -> coalesced 16B ws writes
        char* outb = ws + 4194304 + ((size_t)vt << 14);
        #pragma unroll
        for (int i = 0; i < 4; ++i){
            int c   = tid + 256 * i;              // chunk 0..1023
            int d   = c >> 3;
            int c16 = c & 7;
            int m   = (c16 ^ (d & 7)) << 3;
            unsigned v0 = vlds[(m + 0) * VSTRIDE + d];
            unsigned v1 = vlds[(m + 1) * VSTRIDE + d];
            unsigned v2 = vlds[(m + 2) * VSTRIDE + d];
            unsigned v3 = vlds[(m + 3) * VSTRIDE + d];
            unsigned v4 = vlds[(m + 4) * VSTRIDE + d];
            unsigned v5 = vlds[(m + 5) * VSTRIDE + d];
            unsigned v6 = vlds[(m + 6) * VSTRIDE + d];
            unsigned v7 = vlds[(m + 7) * VSTRIDE + d];
            uint4 w;
            w.x = v0 | (v1 << 16); w.y = v2 | (v3 << 16);
            w.z = v4 | (v5 << 16); w.w = v6 | (v7 << 16);
            *(uint4*)(outb + (size_t)c * 16) = w;
        }
    }
}

// ---------------- main kernel: 4 warps, QT=64 each ----------------
struct Buf { char k1[16384]; char k2[16384]; char vt[16384]; };
union LdsU { Buf buf[2]; float oepi[BLOCK_Q * D]; };   // 96 KiB

__global__ __launch_bounds__(256, 1)
void diffattn(const float* __restrict__ q1, const float* __restrict__ q2,
              const float* __restrict__ ll, const char* __restrict__ ws,
              float* __restrict__ out)
{
    __shared__ LdsU lds;
    const int tid  = threadIdx.x;
    const int lane = tid & 63;
    const int wid  = tid >> 6;       // 0..3
    const int atn  = wid >> 1;       // warps 0-1: attn1, 2-3: attn2
    const int wq   = wid & 1;        // 64-row slice
    const int g    = lane >> 5;
    const int ql   = lane & 31;

    // XCD-chunked swizzle
    const int bid  = blockIdx.x;
    const int sbid = (bid & 7) * 32 + (bid >> 3);
    const int qb   = sbid & 15;
    const int h    = sbid >> 4;
    const int kvh  = h >> 2;

    auto stage = [&](int bsel, int t){
        const char* base = ws + ((size_t)(kvh * NTILE + t) << 14) + (lane << 4);
        char* lb = (char*)&lds.buf[bsel];
        #pragma unroll
        for (int j = 0; j < 12; ++j){
            int ci  = wid * 12 + j;          // 0..47
            int mat = ci >> 4, sub = ci & 15;
            __builtin_amdgcn_global_load_lds(
                (const __attribute__((address_space(1))) void*)(base + (size_t)mat * 2097152 + (sub << 10)),
                (__attribute__((address_space(3))) void*)(lb + mat * 16384 + (sub << 10)),
                16, 0, 0);
        }
    };
    stage(0, 0);

    // ---- Q fragments: qf[qs][dc], B-operand (n=ql, k-slot (g,i) -> d=dc*16+g*8+i) ----
    const float qsc = 0.08838834764831845f * 1.4426950408889634f; // rsqrt(128)*log2(e)
    bf16x8 qf[2][8];
    #pragma unroll
    for (int qs = 0; qs < 2; ++qs){
        const float* Qbase = (atn ? q2 : q1)
            + ((size_t)h * SEQ + (size_t)qb * BLOCK_Q + wq * QT + qs * 32 + ql) * D;
        #pragma unroll
        for (int dc = 0; dc < 8; ++dc){
            const float* p = Qbase + dc * 16 + g * 8;
            f32x4 a = *(const f32x4*)(p);
            f32x4 c = *(const f32x4*)(p + 4);
            union { bf16x8 v; unsigned u[4]; } u;
            u.u[0] = cvtpk(a[0] * qsc, a[1] * qsc);
            u.u[1] = cvtpk(a[2] * qsc, a[3] * qsc);
            u.u[2] = cvtpk(c[0] * qsc, c[1] * qsc);
            u.u[3] = cvtpk(c[2] * qsc, c[3] * qsc);
            qf[qs][dc] = u.v;
        }
    }

    f32x16 ot[2][4];
    #pragma unroll
    for (int qs = 0; qs < 2; ++qs)
        #pragma unroll
        for (int i = 0; i < 4; ++i)
            #pragma unroll
            for (int e = 0; e < 16; ++e) ot[qs][i][e] = 0.f;
    float mrun[2] = {-1e30f, -1e30f}, lrun[2] = {0.f, 0.f};

    __syncthreads();

    for (int t = 0; t < NTILE; ++t){
        const int cur = t & 1;
        if (t + 1 < NTILE) stage(cur ^ 1, t + 1);

        const char* kt = atn ? lds.buf[cur].k2 : lds.buf[cur].k1;
        const char* vt = lds.buf[cur].vt;

        // ---- swapped QK^T: one kf read feeds both q-subtiles ----
        f32x16 st[2][2];
        __builtin_amdgcn_s_setprio(1);
        #pragma unroll
        for (int kb = 0; kb < 2; ++kb){
            #pragma unroll
            for (int qs = 0; qs < 2; ++qs)
                #pragma unroll
                for (int e = 0; e < 16; ++e) st[qs][kb][e] = 0.f;
            const int krow = kb * 32 + ql;
            const int kswz = (krow & 7) << 4;
            #pragma unroll
            for (int dc = 0; dc < 8; ++dc){
                bf16x8 kf = *(const bf16x8*)(kt + ((krow * 256 + dc * 32 + g * 16) ^ kswz));
                st[0][kb] = __builtin_amdgcn_mfma_f32_32x32x16_bf16(kf, qf[0][dc], st[0][kb], 0, 0, 0);
                st[1][kb] = __builtin_amdgcn_mfma_f32_32x32x16_bf16(kf, qf[1][dc], st[1][kb], 0, 0, 0);
            }
        }
        __builtin_amdgcn_s_setprio(0);

        // ---- per-subtile online softmax (exp2 domain, defer-max THR=8) + repack ----
        bf16x8 pb[2][4];
        #pragma unroll
        for (int qs = 0; qs < 2; ++qs){
            float tmax = -1e30f;
            #pragma unroll
            for (int kb = 0; kb < 2; ++kb)
                #pragma unroll
                for (int e = 0; e < 16; ++e) tmax = fmaxf(tmax, st[qs][kb][e]);
            tmax = fmaxf(tmax, __shfl_xor(tmax, 32));
            if (!__all(tmax <= mrun[qs] + 8.f)){
                float mnew = fmaxf(mrun[qs], tmax);
                float corr = exp2f(mrun[qs] - mnew);
                lrun[qs] *= corr;
                #pragma unroll
                for (int i = 0; i < 4; ++i) ot[qs][i] = ot[qs][i] * corr;
                mrun[qs] = mnew;
            }
            float p[2][16];
            float ps = 0.f;
            #pragma unroll
            for (int kb = 0; kb < 2; ++kb)
                #pragma unroll
                for (int e = 0; e < 16; ++e){
                    float pe = exp2f(st[qs][kb][e] - mrun[qs]);
                    p[kb][e] = pe; ps += pe;
                }
            ps += __shfl_xor(ps, 32);
            lrun[qs] += ps;

            unsigned W[2][4][2];
            #pragma unroll
            for (int kb = 0; kb < 2; ++kb)
                #pragma unroll
                for (int hh = 0; hh < 4; ++hh)
                    #pragma unroll
                    for (int jj = 0; jj < 2; ++jj)
                        W[kb][hh][jj] = cvtpk(p[kb][4*hh + 2*jj], p[kb][4*hh + 2*jj + 1]);
            #pragma unroll
            for (int kc = 0; kc < 4; ++kc){
                const int kb = kc >> 1, b0 = 2 * (kc & 1);
                union { bf16x8 v; unsigned u[4]; } pu;
                #pragma unroll
                for (int j = 0; j < 4; ++j){
                    const int gsrc = j >> 1, jj = j & 1;
                    unsigned wlo = W[kb][b0][jj];
                    unsigned whi = W[kb][b0 + 1][jj];
                    unsigned loc = g ? whi : wlo;
                    unsigned oth = g ? wlo : whi;
                    unsigned rem = (unsigned)__shfl_xor((int)oth, 32);
                    pu.u[j] = (gsrc == g) ? loc : rem;
                }
                pb[qs][kc] = pu.v;
            }
        }

        // ---- PV: one vf read feeds both q-subtiles ----
        __builtin_amdgcn_s_setprio(1);
        #pragma unroll
        for (int db = 0; db < 4; ++db){
            const int drow = db * 32 + ql;
            const int vswz = (drow & 7) << 4;
            #pragma unroll
            for (int kc = 0; kc < 4; ++kc){
                bf16x8 vf = *(const bf16x8*)(vt + ((drow * 128 + kc * 32 + g * 16) ^ vswz));
                ot[0][db] = __builtin_amdgcn_mfma_f32_32x32x16_bf16(vf, pb[0][kc], ot[0][db], 0, 0, 0);
                ot[1][db] = __builtin_amdgcn_mfma_f32_32x32x16_bf16(vf, pb[1][kc], ot[1][db], 0, 0, 0);
            }
        }
        __builtin_amdgcn_s_setprio(0);
        __syncthreads();
    }

    // ---- epilogue: combine attn1 - lam*attn2 via LDS ----
    const float lam = expf(ll[0]);

    if (atn == 1){
        #pragma unroll
        for (int qs = 0; qs < 2; ++qs){
            const float s = -lam / lrun[qs];
            const int rowl = wq * QT + qs * 32 + ql;
            const int eswz = (rowl & 7) << 2;
            #pragma unroll
            for (int db = 0; db < 4; ++db)
                #pragma unroll
                for (int e = 0; e < 16; ++e){
                    int d = db * 32 + (e & 3) + 8 * (e >> 2) + 4 * g;
                    lds.oepi[rowl * 128 + (d ^ eswz)] = ot[qs][db][e] * s;
                }
        }
    }
    __syncthreads();
    if (atn == 0){
        #pragma unroll
        for (int qs = 0; qs < 2; ++qs){
            const float inv = 1.f / lrun[qs];
            const int rowl = wq * QT + qs * 32 + ql;
            const int eswz = (rowl & 7) << 2;
            #pragma unroll
            for (int db = 0; db < 4; ++db)
                #pragma unroll
                for (int e = 0; e < 16; ++e){
                    int d = db * 32 + (e & 3) + 8 * (e >> 2) + 4 * g;
                    int idx = rowl * 128 + (d ^ eswz);
                    lds.oepi[idx] = ot[qs][db][e] * inv + lds.oepi[idx];
                }
        }
    }
    __syncthreads();

    const size_t obase = ((size_t)h * SEQ + (size_t)qb * BLOCK_Q) * D;
    const int row = tid >> 1;
    const int ch  = (tid & 1) * 64;
    const int sw  = (row & 7) << 2;
    #pragma unroll
    for (int j = 0; j < 4; ++j){
        int c = ch + j * 16;
        f32x4 val = *(const f32x4*)&lds.oepi[row * 128 + (c ^ sw)];
        *(f32x4*)(out + obase + (size_t)row * D + c) = val;
        c += 4;
        val = *(const f32x4*)&lds.oepi[row * 128 + (c ^ sw)];
        *(f32x4*)(out + obase + (size_t)row * D + c) = val;
        c += 4;
        val = *(const f32x4*)&lds.oepi[row * 128 + (c ^ sw)];
        *(f32x4*)(out + obase + (size_t)row * D + c) = val;
        c += 4;
        val = *(const f32x4*)&lds.oepi[row * 128 + (c ^ sw)];
        *(f32x4*)(out + obase + (size_t)row * D + c) = val;
    }
}

extern "C" void kernel_launch(void* const* d_in, const int* in_sizes, int n_in,
                              void* d_out, int out_size, void* d_ws, size_t ws_size,
                              hipStream_t stream)
{
    (void)in_sizes; (void)n_in; (void)out_size; (void)ws_size;
    const float* q1 = (const float*)d_in[0];
    const float* k1 = (const float*)d_in[1];
    const float* v  = (const float*)d_in[2];
    const float* q2 = (const float*)d_in[3];
    const float* k2 = (const float*)d_in[4];
    const float* ll = (const float*)d_in[5];
    prep<<<1152, 256, 0, stream>>>(k1, k2, v, (char*)d_ws);
    diffattn<<<256, 256, 0, stream>>>(q1, q2, ll, (const char*)d_ws, (float*)d_out);
}

// Round 4
// 198.405 us; speedup vs baseline: 1.1394x; 1.1394x over previous
//
#include <hip/hip_runtime.h>
#include <hip/hip_bf16.h>
#include <stdint.h>

#define D 128
#define SEQ 2048
#define NH 16
#define KVB 32
#define NTILE 64
#define BLOCK_Q 64

typedef float f32x4  __attribute__((ext_vector_type(4)));
typedef float f32x16 __attribute__((ext_vector_type(16)));
typedef short bf16x8 __attribute__((ext_vector_type(8)));

__device__ __forceinline__ unsigned cvtpk(float lo, float hi){
    unsigned r;
    asm("v_cvt_pk_bf16_f32 %0, %1, %2" : "=v"(r) : "v"(lo), "v"(hi));
    return r;
}

// ---------------- prep: f32 -> bf16 pre-swizzled LDS tile images in ws ----------
// K1 [0,2MB):   chunk addr = grow*256 + c16*16, content = K[grow][(c16^(grow&7))*8 ..+8]
// K2 [2MB,4MB): same
// V  [4MB,6MB): per 32-key tile vt2 (8KB): chunk c = d*4+s (d=0..127, s=0..3):
//               content = V[vt2*32 + ((s^(d&3))<<3) + j][d], j=0..7
#define VSTRIDE 130
__global__ __launch_bounds__(256) void prep(const float* __restrict__ k1,
                                            const float* __restrict__ k2,
                                            const float* __restrict__ v,
                                            char* __restrict__ ws)
{
    __shared__ unsigned short vlds[64 * VSTRIDE];
    const int b = blockIdx.x;
    if (b < 1024){
        int cid = b * 256 + threadIdx.x;          // 0..262143
        const float* src = (cid & 131072) ? k2 : k1;
        int r    = cid & 131071;
        int grow = r >> 4;
        int c16  = r & 15;
        const float* p = src + (size_t)grow * D + ((c16 ^ (grow & 7)) << 3);
        f32x4 a = *(const f32x4*)p;
        f32x4 c = *(const f32x4*)(p + 4);
        uint4 w;
        w.x = cvtpk(a[0], a[1]); w.y = cvtpk(a[2], a[3]);
        w.z = cvtpk(c[0], c[1]); w.w = cvtpk(c[2], c[3]);
        *(uint4*)(ws + (size_t)cid * 16) = w;
    } else {
        const int vt  = b - 1024;                 // 0..127, covers keys vt*64..+64
        const int tid = threadIdx.x;
        // load phase: coalesced rows -> LDS bf16 [64][VSTRIDE]
        const int key = tid >> 2, cg = tid & 3;
        const float* vp = v + (size_t)(vt * 64 + key) * D + cg * 32;
        #pragma unroll
        for (int i = 0; i < 8; ++i){
            f32x4 x = *(const f32x4*)(vp + i * 4);
            unsigned lo = cvtpk(x[0], x[1]);
            unsigned hi = cvtpk(x[2], x[3]);
            unsigned* dst = (unsigned*)&vlds[key * VSTRIDE + cg * 32 + i * 4];
            dst[0] = lo; dst[1] = hi;
        }
        __syncthreads();
        // store phase: two 32-key tiles
        #pragma unroll
        for (int tt = 0; tt < 2; ++tt){
            char* outb = ws + 4194304 + (((size_t)vt * 2 + tt) << 13);
            #pragma unroll
            for (int i = 0; i < 2; ++i){
                int c = tid + 256 * i;            // 0..511
                int d = c >> 2;
                int s = c & 3;
                int m = tt * 32 + ((s ^ (d & 3)) << 3);
                unsigned v0 = vlds[(m + 0) * VSTRIDE + d];
                unsigned v1 = vlds[(m + 1) * VSTRIDE + d];
                unsigned v2 = vlds[(m + 2) * VSTRIDE + d];
                unsigned v3 = vlds[(m + 3) * VSTRIDE + d];
                unsigned v4 = vlds[(m + 4) * VSTRIDE + d];
                unsigned v5 = vlds[(m + 5) * VSTRIDE + d];
                unsigned v6 = vlds[(m + 6) * VSTRIDE + d];
                unsigned v7 = vlds[(m + 7) * VSTRIDE + d];
                uint4 w;
                w.x = v0 | (v1 << 16); w.y = v2 | (v3 << 16);
                w.z = v4 | (v5 << 16); w.w = v6 | (v7 << 16);
                *(uint4*)(outb + (size_t)c * 16) = w;
            }
        }
    }
}

// ---------------- main kernel: 4 warps, BLOCK_Q=64, KVB=32, 2 blocks/CU ----------
struct Buf { char k1[8192]; char k2[8192]; char vt[8192]; };
union LdsU { Buf buf[2]; float oepi[BLOCK_Q * D]; };   // 48 KiB

__global__ __launch_bounds__(256, 2)
void diffattn(const float* __restrict__ q1, const float* __restrict__ q2,
              const float* __restrict__ ll, const char* __restrict__ ws,
              float* __restrict__ out)
{
    __shared__ LdsU lds;
    const int tid  = threadIdx.x;
    const int lane = tid & 63;
    const int wid  = tid >> 6;       // 0..3
    const int atn  = wid >> 1;       // warps 0-1: attn1, 2-3: attn2
    const int wq   = wid & 1;        // 32-row slice
    const int g    = lane >> 5;
    const int ql   = lane & 31;

    // XCD-chunked swizzle: XCD x covers logical blocks [x*64,(x+1)*64) = 2 heads
    const int bid  = blockIdx.x;
    const int sbid = (bid & 7) * 64 + (bid >> 3);
    const int qb   = sbid & 31;
    const int h    = sbid >> 5;
    const int kvh  = h >> 2;

    auto stage = [&](int bsel, int t){
        const char* b1 = ws + ((size_t)(kvh * 2048 + t * KVB) << 8);
        const char* b2 = b1 + 2097152;
        const char* bv = ws + 4194304 + ((size_t)(kvh * NTILE + t) << 13);
        char* lb = (char*)&lds.buf[bsel];
        #pragma unroll
        for (int j = 0; j < 6; ++j){
            int ci  = wid * 6 + j;           // 0..23, 1KB chunks
            int mat = ci >> 3, sub = ci & 7;
            const char* gb = (mat == 0) ? b1 : ((mat == 1) ? b2 : bv);
            __builtin_amdgcn_global_load_lds(
                (const __attribute__((address_space(1))) void*)(gb + (sub << 10) + (lane << 4)),
                (__attribute__((address_space(3))) void*)(lb + mat * 8192 + (sub << 10)),
                16, 0, 0);
        }
    };
    stage(0, 0);

    // ---- Q fragments (B-operand: n=ql, k-slot (g,i) -> d = dc*16+g*8+i) ----
    const float* Qbase = (atn ? q2 : q1)
        + ((size_t)h * SEQ + (size_t)qb * BLOCK_Q + wq * 32 + ql) * D;
    const float qsc = 0.08838834764831845f * 1.4426950408889634f; // rsqrt(128)*log2(e)
    bf16x8 qf[8];
    #pragma unroll
    for (int dc = 0; dc < 8; ++dc){
        const float* p = Qbase + dc * 16 + g * 8;
        f32x4 a = *(const f32x4*)(p);
        f32x4 c = *(const f32x4*)(p + 4);
        union { bf16x8 v; unsigned u[4]; } u;
        u.u[0] = cvtpk(a[0] * qsc, a[1] * qsc);
        u.u[1] = cvtpk(a[2] * qsc, a[3] * qsc);
        u.u[2] = cvtpk(c[0] * qsc, c[1] * qsc);
        u.u[3] = cvtpk(c[2] * qsc, c[3] * qsc);
        qf[dc] = u.v;
    }

    f32x16 ot[4];
    #pragma unroll
    for (int i = 0; i < 4; ++i)
        #pragma unroll
        for (int e = 0; e < 16; ++e) ot[i][e] = 0.f;
    float mrun = 0.f, lrun = 0.f;   // mrun=0 init valid: p <= 2^8 bounded (defer-max)

    __syncthreads();

    for (int t = 0; t < NTILE; ++t){
        const int cur = t & 1;
        if (t + 1 < NTILE) stage(cur ^ 1, t + 1);

        const char* kt = atn ? lds.buf[cur].k2 : lds.buf[cur].k1;
        const char* vtp = lds.buf[cur].vt;

        // ---- swapped QK^T with C-init = -mrun (folds the softmax subtract) ----
        f32x16 st;
        const float negm = -mrun;
        #pragma unroll
        for (int e = 0; e < 16; ++e) st[e] = negm;
        const int kswz = (ql & 7) << 4;
        __builtin_amdgcn_s_setprio(1);
        #pragma unroll
        for (int dc = 0; dc < 8; ++dc){
            bf16x8 kf = *(const bf16x8*)(kt + ((ql * 256 + dc * 32 + g * 16) ^ kswz));
            st = __builtin_amdgcn_mfma_f32_32x32x16_bf16(kf, qf[dc], st, 0, 0, 0);
        }
        __builtin_amdgcn_s_setprio(0);

        // ---- online softmax (exp2 domain, relative values, defer-max THR=8) ----
        float tmax = st[0];
        #pragma unroll
        for (int e = 1; e < 16; ++e) tmax = fmaxf(tmax, st[e]);
        tmax = fmaxf(tmax, __shfl_xor(tmax, 32));
        if (!__all(tmax <= 8.f)){
            float tpos = fmaxf(tmax, 0.f);
            float corr = exp2f(-tpos);
            lrun *= corr;
            #pragma unroll
            for (int i = 0; i < 4; ++i) ot[i] = ot[i] * corr;
            mrun += tpos;
            #pragma unroll
            for (int e = 0; e < 16; ++e) st[e] -= tpos;
        }
        float p[16];
        float ps = 0.f;
        #pragma unroll
        for (int e = 0; e < 16; ++e){
            float pe = exp2f(st[e]);
            p[e] = pe; ps += pe;
        }
        ps += __shfl_xor(ps, 32);
        lrun += ps;

        // ---- repack P -> bf16 B-frags; key(e) = (e&3)+8*(e>>2)+4g ----
        unsigned W[4][2];
        #pragma unroll
        for (int hh = 0; hh < 4; ++hh)
            #pragma unroll
            for (int jj = 0; jj < 2; ++jj)
                W[hh][jj] = cvtpk(p[4*hh + 2*jj], p[4*hh + 2*jj + 1]);
        bf16x8 pb[2];
        #pragma unroll
        for (int kc = 0; kc < 2; ++kc){
            unsigned a0 = W[2*kc][0],   a1 = W[2*kc][1];
            unsigned b0 = W[2*kc+1][0], b1 = W[2*kc+1][1];
            unsigned loc0 = g ? b0 : a0, loc1 = g ? b1 : a1;
            unsigned snd0 = g ? a0 : b0, snd1 = g ? a1 : b1;
            unsigned rem0 = (unsigned)__shfl_xor((int)snd0, 32);
            unsigned rem1 = (unsigned)__shfl_xor((int)snd1, 32);
            union { bf16x8 v; unsigned u[4]; } pu;
            pu.u[0] = g ? rem0 : loc0;
            pu.u[1] = g ? rem1 : loc1;
            pu.u[2] = g ? loc0 : rem0;
            pu.u[3] = g ? loc1 : rem1;
            pb[kc] = pu.v;
        }

        // ---- PV: O^T += V^T · P^T  (V tile [128][64B], swizzle s^=(d&3)) ----
        __builtin_amdgcn_s_setprio(1);
        #pragma unroll
        for (int db = 0; db < 4; ++db){
            const int drow = db * 32 + ql;
            #pragma unroll
            for (int kc = 0; kc < 2; ++kc){
                int s = (kc * 2 + g) ^ (drow & 3);
                bf16x8 vf = *(const bf16x8*)(vtp + drow * 64 + s * 16);
                ot[db] = __builtin_amdgcn_mfma_f32_32x32x16_bf16(vf, pb[kc], ot[db], 0, 0, 0);
            }
        }
        __builtin_amdgcn_s_setprio(0);
        __syncthreads();
    }

    // ---- epilogue: combine attn1 - lam*attn2 via LDS ----
    const float lam = expf(ll[0]);
    const int rowl = wq * 32 + ql;
    const int eswz = (rowl & 7) << 2;

    if (atn == 1){
        const float s = -lam / lrun;
        #pragma unroll
        for (int db = 0; db < 4; ++db)
            #pragma unroll
            for (int e = 0; e < 16; ++e){
                int d = db * 32 + (e & 3) + 8 * (e >> 2) + 4 * g;
                lds.oepi[rowl * 128 + (d ^ eswz)] = ot[db][e] * s;
            }
    }
    __syncthreads();
    if (atn == 0){
        const float inv = 1.f / lrun;
        #pragma unroll
        for (int db = 0; db < 4; ++db)
            #pragma unroll
            for (int e = 0; e < 16; ++e){
                int d = db * 32 + (e & 3) + 8 * (e >> 2) + 4 * g;
                int idx = rowl * 128 + (d ^ eswz);
                lds.oepi[idx] = ot[db][e] * inv + lds.oepi[idx];
            }
    }
    __syncthreads();

    const size_t obase = ((size_t)h * SEQ + (size_t)qb * BLOCK_Q) * D;
    const int row = tid >> 2;            // 0..63
    const int qc  = tid & 3;
    const int sw  = (row & 7) << 2;
    #pragma unroll
    for (int j = 0; j < 8; ++j){
        int c = qc * 32 + j * 4;
        f32x4 val = *(const f32x4*)&lds.oepi[row * 128 + (c ^ sw)];
        *(f32x4*)(out + obase + (size_t)row * D + c) = val;
    }
}

extern "C" void kernel_launch(void* const* d_in, const int* in_sizes, int n_in,
                              void* d_out, int out_size, void* d_ws, size_t ws_size,
                              hipStream_t stream)
{
    (void)in_sizes; (void)n_in; (void)out_size; (void)ws_size;
    const float* q1 = (const float*)d_in[0];
    const float* k1 = (const float*)d_in[1];
    const float* v  = (const float*)d_in[2];
    const float* q2 = (const float*)d_in[3];
    const float* k2 = (const float*)d_in[4];
    const float* ll = (const float*)d_in[5];
    prep<<<1152, 256, 0, stream>>>(k1, k2, v, (char*)d_ws);
    diffattn<<<512, 256, 0, stream>>>(q1, q2, ll, (const char*)d_ws, (float*)d_out);
}

// Round 7
// 188.419 us; speedup vs baseline: 1.1997x; 1.0530x over previous
//
#include <hip/hip_runtime.h>
#include <hip/hip_bf16.h>
#include <stdint.h>

#define D 128
#define SEQ 2048
#define NH 16
#define KVB 32
#define NTILE 64
#define QT 32

typedef float f32x4  __attribute__((ext_vector_type(4)));
typedef float f32x16 __attribute__((ext_vector_type(16)));
typedef short bf16x8 __attribute__((ext_vector_type(8)));

__device__ __forceinline__ unsigned cvtpk(float lo, float hi){
    unsigned r;
    asm("v_cvt_pk_bf16_f32 %0, %1, %2" : "=v"(r) : "v"(lo), "v"(hi));
    return r;
}

// ---------------- prep: build lane-major MFMA fragment images in ws -------------
// K1 [0,2MB):  tile (kvh,t) at ((kvh*64+t)<<13); chunk (dc,l) at +dc*1024+l*16 =
//              K1[kvh*2048 + t*32 + (l&31)][dc*16 + (l>>5)*8 .. +8]  (bf16x8)
// K2 [2MB,4MB): same layout
// V  [4MB,6MB): tile at same index; chunk (r,l), r=db*2+kc:
//              V[kvh*2048 + t*32 + kc*16 + (l>>5)*8 + j][db*32 + (l&31)], j=0..7
#define VSTRIDE 130
__global__ __launch_bounds__(256) void prep(const float* __restrict__ k1,
                                            const float* __restrict__ k2,
                                            const float* __restrict__ v,
                                            char* __restrict__ ws)
{
    __shared__ unsigned short vlds[64 * VSTRIDE];
    const int b = blockIdx.x;
    if (b < 1024){
        int cid  = b * 256 + threadIdx.x;        // 0..262143
        int mat  = cid >> 17;
        int r    = cid & 131071;
        int grow = r >> 4;                       // global K row 0..8191
        int dseg = r & 15;                       // 8-float segment
        const float* src = mat ? k2 : k1;
        const float* p = src + (size_t)grow * D + dseg * 8;
        f32x4 a = *(const f32x4*)p;
        f32x4 c = *(const f32x4*)(p + 4);
        uint4 w;
        w.x = cvtpk(a[0], a[1]); w.y = cvtpk(a[2], a[3]);
        w.z = cvtpk(c[0], c[1]); w.w = cvtpk(c[2], c[3]);
        int kvh = grow >> 11, t = (grow >> 5) & 63, key = grow & 31;
        int dc = dseg >> 1, gh = dseg & 1;
        char* dst = ws + (size_t)mat * 2097152
                  + ((size_t)(kvh * 64 + t) << 13) + dc * 1024 + (gh * 32 + key) * 16;
        *(uint4*)dst = w;
    } else {
        const int vb  = b - 1024;                // 0..127: 64-key block
        const int tid = threadIdx.x;
        const int key = tid >> 2, cg = tid & 3;
        const float* vp = v + (size_t)(vb * 64 + key) * D + cg * 32;
        #pragma unroll
        for (int i = 0; i < 8; ++i){
            f32x4 x = *(const f32x4*)(vp + i * 4);
            unsigned lo = cvtpk(x[0], x[1]);
            unsigned hi = cvtpk(x[2], x[3]);
            unsigned* dst = (unsigned*)&vlds[key * VSTRIDE + cg * 32 + i * 4];
            dst[0] = lo; dst[1] = hi;
        }
        __syncthreads();
        #pragma unroll
        for (int it = 0; it < 4; ++it){
            int c  = tid + 256 * it;             // 0..1023
            int tt = c >> 9;
            int cc = c & 511;
            int r  = cc >> 6;                    // db*2+kc
            int l  = cc & 63;
            int db = r >> 1, kc = r & 1;
            int m  = tt * 32 + kc * 16 + (l >> 5) * 8;   // key base in block
            int dd = db * 32 + (l & 31);
            unsigned v0 = vlds[(m + 0) * VSTRIDE + dd];
            unsigned v1 = vlds[(m + 1) * VSTRIDE + dd];
            unsigned v2 = vlds[(m + 2) * VSTRIDE + dd];
            unsigned v3 = vlds[(m + 3) * VSTRIDE + dd];
            unsigned v4 = vlds[(m + 4) * VSTRIDE + dd];
            unsigned v5 = vlds[(m + 5) * VSTRIDE + dd];
            unsigned v6 = vlds[(m + 6) * VSTRIDE + dd];
            unsigned v7 = vlds[(m + 7) * VSTRIDE + dd];
            uint4 w;
            w.x = v0 | (v1 << 16); w.y = v2 | (v3 << 16);
            w.z = v4 | (v5 << 16); w.w = v6 | (v7 << 16);
            char* dst = ws + 4194304 + ((size_t)(vb * 2 + tt) << 13) + r * 1024 + l * 16;
            *(uint4*)dst = w;
        }
    }
}

// ---------------- main kernel: 2 warps, reg-staged K/V, barrier-free loop -------
__global__ __launch_bounds__(128, 2)
void diffattn(const float* __restrict__ q1, const float* __restrict__ q2,
              const float* __restrict__ ll, const char* __restrict__ ws,
              float* __restrict__ out)
{
    __shared__ float oepi[QT * D];   // 16 KiB
    const int tid  = threadIdx.x;
    const int lane = tid & 63;
    const int atn  = tid >> 6;       // warp 0: attn1, warp 1: attn2
    const int g    = lane >> 5;
    const int ql   = lane & 31;

    // XCD swizzle: 1024 blocks, 128/XCD; co-resident blocks get consecutive qb
    const int bid  = blockIdx.x;
    const int sbid = (bid & 7) * 128 + (bid >> 3);
    const int qb   = sbid & 63;
    const int h    = sbid >> 6;
    const int kvh  = h >> 2;

    const char* kbase = ws + (size_t)atn * 2097152 + ((size_t)(kvh * 64) << 13);
    const char* vbase = ws + 4194304 + ((size_t)(kvh * 64) << 13);
    const int loff = lane * 16;

    // ---- stage tile 0 into registers ----
    bf16x8 ak[8], av[8];
    #pragma unroll
    for (int r = 0; r < 8; ++r) ak[r] = *(const bf16x8*)(kbase + r * 1024 + loff);
    #pragma unroll
    for (int r = 0; r < 8; ++r) av[r] = *(const bf16x8*)(vbase + r * 1024 + loff);

    // ---- Q fragments (B-operand: n=ql, k-slot (g,j) -> d = dc*16+g*8+j) ----
    const float* Qbase = (atn ? q2 : q1)
        + ((size_t)h * SEQ + (size_t)qb * QT + ql) * D;
    const float qsc = 0.08838834764831845f * 1.4426950408889634f; // rsqrt(128)*log2(e)
    bf16x8 qf[8];
    #pragma unroll
    for (int dc = 0; dc < 8; ++dc){
        const float* p = Qbase + dc * 16 + g * 8;
        f32x4 a = *(const f32x4*)(p);
        f32x4 c = *(const f32x4*)(p + 4);
        union { bf16x8 v; unsigned u[4]; } u;
        u.u[0] = cvtpk(a[0] * qsc, a[1] * qsc);
        u.u[1] = cvtpk(a[2] * qsc, a[3] * qsc);
        u.u[2] = cvtpk(c[0] * qsc, c[1] * qsc);
        u.u[3] = cvtpk(c[2] * qsc, c[3] * qsc);
        qf[dc] = u.v;
    }

    f32x16 ot[4];
    #pragma unroll
    for (int i = 0; i < 4; ++i)
        #pragma unroll
        for (int e = 0; e < 16; ++e) ot[i][e] = 0.f;
    float mrun = 0.f, lrun = 0.f;    // defer-max: p bounded by 2^8, harmless in f32

    for (int t = 0; t < NTILE; ++t){
        const int tn = (t + 1 < NTILE) ? t + 1 : t;

        // ---- swapped QK^T, C-init = -mrun ----
        f32x16 st;
        const float negm = -mrun;
        #pragma unroll
        for (int e = 0; e < 16; ++e) st[e] = negm;
        __builtin_amdgcn_s_setprio(1);
        #pragma unroll
        for (int dc = 0; dc < 8; ++dc)
            st = __builtin_amdgcn_mfma_f32_32x32x16_bf16(ak[dc], qf[dc], st, 0, 0, 0);
        __builtin_amdgcn_s_setprio(0);

        // ---- prefetch K(t+1): ak consumed, reload (lands during softmax+PV) ----
        {
            const char* kp = kbase + ((size_t)tn << 13);
            #pragma unroll
            for (int r = 0; r < 8; ++r) ak[r] = *(const bf16x8*)(kp + r * 1024 + loff);
        }

        // ---- online softmax (exp2 domain, defer-max THR=8) ----
        float tmax = st[0];
        #pragma unroll
        for (int e = 1; e < 16; ++e) tmax = fmaxf(tmax, st[e]);
        tmax = fmaxf(tmax, __shfl_xor(tmax, 32));
        if (!__all(tmax <= 8.f)){
            float tpos = fmaxf(tmax, 0.f);
            float corr = exp2f(-tpos);
            lrun *= corr;
            #pragma unroll
            for (int i = 0; i < 4; ++i) ot[i] = ot[i] * corr;
            mrun += tpos;
            #pragma unroll
            for (int e = 0; e < 16; ++e) st[e] -= tpos;
        }
        float p[16];
        float ps = 0.f;
        #pragma unroll
        for (int e = 0; e < 16; ++e){
            float pe = exp2f(st[e]);
            p[e] = pe; ps += pe;
        }
        ps += __shfl_xor(ps, 32);
        lrun += ps;

        // ---- repack P -> bf16 B-frags; key(e) = (e&3)+8*(e>>2)+4g ----
        unsigned W[4][2];
        #pragma unroll
        for (int hh = 0; hh < 4; ++hh)
            #pragma unroll
            for (int jj = 0; jj < 2; ++jj)
                W[hh][jj] = cvtpk(p[4*hh + 2*jj], p[4*hh + 2*jj + 1]);
        bf16x8 pb[2];
        #pragma unroll
        for (int kc = 0; kc < 2; ++kc){
            unsigned a0 = W[2*kc][0],   a1 = W[2*kc][1];
            unsigned b0 = W[2*kc+1][0], b1 = W[2*kc+1][1];
            unsigned loc0 = g ? b0 : a0, loc1 = g ? b1 : a1;
            unsigned snd0 = g ? a0 : b0, snd1 = g ? a1 : b1;
            unsigned rem0 = (unsigned)__shfl_xor((int)snd0, 32);
            unsigned rem1 = (unsigned)__shfl_xor((int)snd1, 32);
            union { bf16x8 v; unsigned u[4]; } pu;
            pu.u[0] = g ? rem0 : loc0;
            pu.u[1] = g ? rem1 : loc1;
            pu.u[2] = g ? loc0 : rem0;
            pu.u[3] = g ? loc1 : rem1;
            pb[kc] = pu.v;
        }

        // ---- PV: O^T += V^T · P^T  (av[db*2+kc] = V^T fragment) ----
        __builtin_amdgcn_s_setprio(1);
        #pragma unroll
        for (int db = 0; db < 4; ++db){
            ot[db] = __builtin_amdgcn_mfma_f32_32x32x16_bf16(av[db*2+0], pb[0], ot[db], 0, 0, 0);
            ot[db] = __builtin_amdgcn_mfma_f32_32x32x16_bf16(av[db*2+1], pb[1], ot[db], 0, 0, 0);
        }
        __builtin_amdgcn_s_setprio(0);

        // ---- prefetch V(t+1) (lands during next QK + softmax) ----
        {
            const char* vp = vbase + ((size_t)tn << 13);
            #pragma unroll
            for (int r = 0; r < 8; ++r) av[r] = *(const bf16x8*)(vp + r * 1024 + loff);
        }
    }

    // ---- epilogue: combine attn1 - lam*attn2 via LDS ----
    const float lam = expf(ll[0]);
    const int eswz = (ql & 7) << 2;

    if (atn == 1){
        const float s = -lam / lrun;
        #pragma unroll
        for (int db = 0; db < 4; ++db)
            #pragma unroll
            for (int e = 0; e < 16; ++e){
                int d = db * 32 + (e & 3) + 8 * (e >> 2) + 4 * g;
                oepi[ql * 128 + (d ^ eswz)] = ot[db][e] * s;
            }
    }
    __syncthreads();
    if (atn == 0){
        const float inv = 1.f / lrun;
        #pragma unroll
        for (int db = 0; db < 4; ++db)
            #pragma unroll
            for (int e = 0; e < 16; ++e){
                int d = db * 32 + (e & 3) + 8 * (e >> 2) + 4 * g;
                int idx = ql * 128 + (d ^ eswz);
                oepi[idx] = ot[db][e] * inv + oepi[idx];
            }
    }
    __syncthreads();

    const size_t obase = ((size_t)h * SEQ + (size_t)qb * QT) * D;
    const int row = tid >> 2;            // 0..31
    const int qc  = tid & 3;
    const int sw  = (row & 7) << 2;
    #pragma unroll
    for (int j = 0; j < 8; ++j){
        int c = qc * 32 + j * 4;
        f32x4 val = *(const f32x4*)&oepi[row * 128 + (c ^ sw)];
        *(f32x4*)(out + obase + (size_t)row * D + c) = val;
    }
}

extern "C" void kernel_launch(void* const* d_in, const int* in_sizes, int n_in,
                              void* d_out, int out_size, void* d_ws, size_t ws_size,
                              hipStream_t stream)
{
    (void)in_sizes; (void)n_in; (void)out_size; (void)ws_size;
    const float* q1 = (const float*)d_in[0];
    const float* k1 = (const float*)d_in[1];
    const float* v  = (const float*)d_in[2];
    const float* q2 = (const float*)d_in[3];
    const float* k2 = (const float*)d_in[4];
    const float* ll = (const float*)d_in[5];
    prep<<<1152, 256, 0, stream>>>(k1, k2, v, (char*)d_ws);
    diffattn<<<1024, 128, 0, stream>>>(q1, q2, ll, (const char*)d_ws, (float*)d_out);
}